// Round 1
// baseline (1390.778 us; speedup 1.0000x reference)
//
// MultiheadSelectiveAttentionWithTokenPruning — MI355X round 0
//
// Pipeline (all on `stream`, graph-capture safe, no statics):
//  1  cast_x      : X fp32 -> Xhi/Xlo bf16 (split for bf16x3 GEMM)
//  2  cast_w x4   : W fp32 -> W^T bf16 (hi[+lo for Wq/Wk]) (transposed so GEMM
//                   B-frags are contiguous 16B LDS reads, same addressing as A)
//  3  gemm split  : Yq = X@Wq  (hi*hi + hi*lo + lo*hi)  ~fp32 accuracy
//  4  gemm split  : Yk = X@Wk
//  5  gemm        : Yv = X@Wv  (plain bf16 — only feeds attention values)
//  6  lnpack      : LN(Yq) -> Qb bf16 (B,H,N,Dh) + q0s fp32 (head-0, selection)
//  7  lnpack      : LN(Yk) -> Kb + k0s
//  8  lnpack      : Yv -> Vb (cast only)
//  9  s_kernel    : S[b,n,m] = relu(q0s.k0s/8), causal/diag/col0-zeroed (fp32)
// 10  p_kernel    : column partial sums of S rows 0..1023 (8 chunks)
// 11  evict       : 1024 sequential argmax evictions. Candidates at step i are
//                   exactly all unevicted tokens <= i -> dense register
//                   accumulators + validity bitmask; tie-break = smallest key
//                   (matches jnp.argmax first-max over the sorted index list).
// 12  flash       : all 16 heads, online softmax, mask = causal && n<evt[m]
// 13  gemm        : out = Ob @ Wo -> d_out fp32
//
// ws overlays: Ob reuses Xhi slot (dead after step 5); S reuses Yq+Yk slots
// (dead after steps 6/7). Peak ws ~107.1 MB.

#include <hip/hip_runtime.h>

#define B_    2
#define N_    2048
#define D_    1024
#define H_    16
#define DH_   64
#define M_    2048
#define ROWS_ 4096
#define BUD_  1024

typedef unsigned short u16;
typedef unsigned int   u32;
typedef unsigned long long u64;
typedef __attribute__((ext_vector_type(8))) short short8;
typedef __attribute__((ext_vector_type(4))) float floatx4;

__device__ __forceinline__ u16 f2b(float f) {
    u32 u = __float_as_uint(f);
    return (u16)((u + 0x7FFFu + ((u >> 16) & 1u)) >> 16);   // RNE
}
__device__ __forceinline__ float b2f(u16 h) {
    return __uint_as_float(((u32)h) << 16);
}

// ---------------------------------------------------------------- cast X
__global__ __launch_bounds__(256) void cast_x_kernel(
    const float* __restrict__ X, u16* __restrict__ Xhi, u16* __restrict__ Xlo)
{
    int idx = (blockIdx.x * 256 + threadIdx.x) * 4;
    float4 v = *(const float4*)&X[idx];
    u16 h0 = f2b(v.x), h1 = f2b(v.y), h2 = f2b(v.z), h3 = f2b(v.w);
    ushort4 hv; hv.x = h0; hv.y = h1; hv.z = h2; hv.w = h3;
    *(ushort4*)&Xhi[idx] = hv;
    ushort4 lv;
    lv.x = f2b(v.x - b2f(h0)); lv.y = f2b(v.y - b2f(h1));
    lv.z = f2b(v.z - b2f(h2)); lv.w = f2b(v.w - b2f(h3));
    *(ushort4*)&Xlo[idx] = lv;
}

// ------------------------------------------------- cast + transpose W
__global__ __launch_bounds__(1024) void cast_w_kernel(
    const float* __restrict__ W, u16* __restrict__ Whi, u16* __restrict__ Wlo,
    int do_lo)
{
    __shared__ float tile[32][33];
    int tx = threadIdx.x, ty = threadIdx.y;
    int x = blockIdx.x * 32 + tx, y = blockIdx.y * 32 + ty;
    tile[ty][tx] = W[(size_t)y * D_ + x];
    __syncthreads();
    float v = tile[tx][ty];
    int n = blockIdx.x * 32 + ty, k = blockIdx.y * 32 + tx;
    u16 h = f2b(v);
    Whi[(size_t)n * D_ + k] = h;
    if (do_lo) Wlo[(size_t)n * D_ + k] = f2b(v - b2f(h));
}

// ------------------------------------------------------------- GEMM
// C[4096][1024] = A[4096][1024] @ Bt^T   (Bt stored [n][k])
// mode 1: C = Ah*Bh + Ah*Bl + Al*Bh  (bf16x3 split, ~fp32 precision)
__global__ __launch_bounds__(256) void gemm_kernel(
    const u16* __restrict__ Ah, const u16* __restrict__ Al,
    const u16* __restrict__ Bh, const u16* __restrict__ Bl,
    int mode, float* __restrict__ C)
{
    __shared__ __align__(16) u16 sAh[128 * 32];
    __shared__ __align__(16) u16 sBh[128 * 32];
    __shared__ __align__(16) u16 sAl[128 * 32];
    __shared__ __align__(16) u16 sBl[128 * 32];
    int tid = threadIdx.x;
    int lane = tid & 63, wv = tid >> 6;
    int wr = wv >> 1, wc = wv & 1;
    int quad = lane >> 4, l16 = lane & 15;
    int m0 = blockIdx.y * 128, n0 = blockIdx.x * 128;

    floatx4 acc[4][4];
    floatx4 zero = {0.f, 0.f, 0.f, 0.f};
#pragma unroll
    for (int i = 0; i < 4; ++i)
#pragma unroll
        for (int j = 0; j < 4; ++j) acc[i][j] = zero;

    for (int k0 = 0; k0 < 1024; k0 += 32) {
#pragma unroll
        for (int it = 0; it < 2; ++it) {
            int e = (tid + it * 256) * 8;
            int r = e >> 5, c = e & 31;
            *(uint4*)&sAh[e] = *(const uint4*)&Ah[(size_t)(m0 + r) * 1024 + k0 + c];
            *(uint4*)&sBh[e] = *(const uint4*)&Bh[(size_t)(n0 + r) * 1024 + k0 + c];
            if (mode) {
                *(uint4*)&sAl[e] = *(const uint4*)&Al[(size_t)(m0 + r) * 1024 + k0 + c];
                *(uint4*)&sBl[e] = *(const uint4*)&Bl[(size_t)(n0 + r) * 1024 + k0 + c];
            }
        }
        __syncthreads();
        short8 ah[4], al[4], bh[4], bl[4];
#pragma unroll
        for (int x = 0; x < 4; ++x) {
            int ra = (wr * 64 + x * 16 + l16) * 32 + quad * 8;
            int rb = (wc * 64 + x * 16 + l16) * 32 + quad * 8;
            ah[x] = *(const short8*)&sAh[ra];
            bh[x] = *(const short8*)&sBh[rb];
            if (mode) {
                al[x] = *(const short8*)&sAl[ra];
                bl[x] = *(const short8*)&sBl[rb];
            }
        }
#pragma unroll
        for (int mi = 0; mi < 4; ++mi)
#pragma unroll
            for (int ni = 0; ni < 4; ++ni) {
                acc[mi][ni] = __builtin_amdgcn_mfma_f32_16x16x32_bf16(
                    ah[mi], bh[ni], acc[mi][ni], 0, 0, 0);
                if (mode) {
                    acc[mi][ni] = __builtin_amdgcn_mfma_f32_16x16x32_bf16(
                        ah[mi], bl[ni], acc[mi][ni], 0, 0, 0);
                    acc[mi][ni] = __builtin_amdgcn_mfma_f32_16x16x32_bf16(
                        al[mi], bh[ni], acc[mi][ni], 0, 0, 0);
                }
            }
        __syncthreads();
    }
    // C/D layout: col = lane&15, row = (lane>>4)*4 + reg   [verified m89/m91]
#pragma unroll
    for (int mi = 0; mi < 4; ++mi)
#pragma unroll
        for (int ni = 0; ni < 4; ++ni)
#pragma unroll
            for (int r = 0; r < 4; ++r) {
                int row = m0 + wr * 64 + mi * 16 + quad * 4 + r;
                int col = n0 + wc * 64 + ni * 16 + l16;
                C[(size_t)row * 1024 + col] = acc[mi][ni][r];
            }
}

// ----------------------------------------------------- LayerNorm + pack
__global__ __launch_bounds__(256) void lnpack_kernel(
    const float* __restrict__ Y, const float* __restrict__ gamma,
    const float* __restrict__ beta, u16* __restrict__ Pk,
    float* __restrict__ head0, int do_ln)
{
    int r = blockIdx.x;
    int tid = threadIdx.x;
    float4 v = *(const float4*)&Y[(size_t)r * D_ + tid * 4];
    float mu = 0.f, rsig = 1.f;
    __shared__ float sS[4], sQ[4];
    if (do_ln) {
        float s = v.x + v.y + v.z + v.w;
        float q = v.x * v.x + v.y * v.y + v.z * v.z + v.w * v.w;
#pragma unroll
        for (int d = 1; d < 64; d <<= 1) { s += __shfl_xor(s, d); q += __shfl_xor(q, d); }
        if ((tid & 63) == 0) { sS[tid >> 6] = s; sQ[tid >> 6] = q; }
        __syncthreads();
        s = sS[0] + sS[1] + sS[2] + sS[3];
        q = sQ[0] + sQ[1] + sQ[2] + sQ[3];
        mu = s * (1.f / 1024.f);
        float var = q * (1.f / 1024.f) - mu * mu;
        rsig = rsqrtf(var + 1e-5f);
    }
    int b = r >> 11, n = r & 2047;
    float xs[4] = {v.x, v.y, v.z, v.w};
#pragma unroll
    for (int j = 0; j < 4; ++j) {
        int c = tid * 4 + j;
        float val = do_ln ? ((xs[j] - mu) * rsig * gamma[c] + beta[c]) : xs[j];
        int h = c >> 6, dh = c & 63;
        Pk[(((size_t)b * H_ + h) * N_ + n) * DH_ + dh] = f2b(val);
        if (head0 && c < 64) head0[(size_t)r * 64 + c] = val;
    }
}

// -------------------------------------------- head-0 selection scores S
__global__ void s_kernel(const float* __restrict__ q0,
                         const float* __restrict__ k0, float* __restrict__ S)
{
    int b = blockIdx.z;
    int n0 = blockIdx.y * 16, m0 = blockIdx.x * 16;
    int tx = threadIdx.x, ty = threadIdx.y;
    int n = n0 + ty, m = m0 + tx;
    float* out = S + ((size_t)b * N_ + n) * M_ + m;
    if (m0 > n0 + 15) { *out = 0.f; return; }   // fully above diagonal
    __shared__ float sq[16][65], sk[16][65];
    int tid = ty * 16 + tx;
    {
        int rr = tid >> 4, cc = (tid & 15) * 4;
        float4 qa = *(const float4*)&q0[((size_t)b * N_ + n0 + rr) * 64 + cc];
        sq[rr][cc] = qa.x; sq[rr][cc + 1] = qa.y; sq[rr][cc + 2] = qa.z; sq[rr][cc + 3] = qa.w;
        float4 ka = *(const float4*)&k0[((size_t)b * N_ + m0 + rr) * 64 + cc];
        sk[rr][cc] = ka.x; sk[rr][cc + 1] = ka.y; sk[rr][cc + 2] = ka.z; sk[rr][cc + 3] = ka.w;
    }
    __syncthreads();
    float acc = 0.f;
#pragma unroll 8
    for (int d = 0; d < 64; ++d) acc += sq[ty][d] * sk[tx][d];
    // causal (m>n) -> relu(-inf)=0 ; diagonal m==n -> 0 ; col 0 -> 0
    float val = (m >= n || m == 0) ? 0.f : fmaxf(acc * 0.125f, 0.f);
    if (m < n && m != 0) val = fmaxf(acc * 0.125f, 0.f); else val = 0.f;
    *out = val;
}

// -------------------------------- partial column sums of S rows 0..1023
__global__ __launch_bounds__(256) void p_kernel(const float* __restrict__ S,
                                                float* __restrict__ P)
{
    int b = blockIdx.z, c = blockIdx.y;
    int m = blockIdx.x * 256 + threadIdx.x;
    const float* base = S + ((size_t)b * N_ + c * 128) * M_ + m;
    float s = 0.f;
    for (int j = 0; j < 128; ++j) s += base[(size_t)j * M_];
    P[((size_t)b * 8 + c) * M_ + m] = s;
}

// --------------------------------------------- sequential greedy eviction
// Candidates at step i == all unevicted tokens <= i  (the kept list stays
// sorted, so jnp.argmax first-max == smallest key among maxima).
__global__ __launch_bounds__(256) void evict_kernel(
    const float* __restrict__ S, const float* __restrict__ P,
    int* __restrict__ evt)
{
    int b = blockIdx.x, t = threadIdx.x;
    __shared__ u64 wred[4];
    float cum[8];
#pragma unroll
    for (int j = 0; j < 8; ++j) {
        float s = 0.f;
#pragma unroll
        for (int c = 0; c < 8; ++c) s += P[((size_t)b * 8 + c) * M_ + t + 256 * j];
        cum[j] = s;
        evt[b * M_ + t + 256 * j] = 0x3FFFFFFF;
    }
    u32 valid = 0x0Fu;              // tokens t+256j for j<4  (m < 1024)
    __syncthreads();
    for (int i = BUD_; i < M_; ++i) {
        const float* Srow = S + ((size_t)b * N_ + i) * M_;
        float rr[8];
#pragma unroll
        for (int j = 0; j < 8; ++j) rr[j] = Srow[t + 256 * j];   // prefetch
        if ((i & 255) == t) valid |= 1u << (i >> 8);             // insert token i
        u64 best = 0;
#pragma unroll
        for (int j = 0; j < 8; ++j)
            if (valid & (1u << j)) {
                u64 u = ((u64)__float_as_uint(cum[j]) << 32) |
                        (u32)(2048 - (t + 256 * j));             // tie -> min m
                if (u > best) best = u;
            }
#pragma unroll
        for (int d = 1; d < 64; d <<= 1) {
            u64 o = __shfl_xor(best, d);
            if (o > best) best = o;
        }
        if ((t & 63) == 0) wred[t >> 6] = best;
        __syncthreads();
        u64 f0 = wred[0] > wred[1] ? wred[0] : wred[1];
        u64 f1 = wred[2] > wred[3] ? wred[2] : wred[3];
        u64 f = f0 > f1 ? f0 : f1;
        __syncthreads();
        int mstar = 2048 - (int)(f & 0xFFFFFFFFull);
        if ((mstar & 255) == t) {
            valid &= ~(1u << (mstar >> 8));
            evt[b * M_ + mstar] = i;
        }
#pragma unroll
        for (int j = 0; j < 8; ++j) cum[j] += rr[j];             // Fm[i] -> Fm[i+1]
    }
}

// ------------------------------------------------------ flash attention
__global__ __launch_bounds__(256) void flash_kernel(
    const u16* __restrict__ Qb, const u16* __restrict__ Kb,
    const u16* __restrict__ Vb, const int* __restrict__ evt,
    u16* __restrict__ Ob)
{
    int bh = blockIdx.y;
    int b = bh >> 4, h = bh & 15;
    int q0 = blockIdx.x * 64;
    int tid = threadIdx.x, lane = tid & 63, w = tid >> 6;
    int quad = lane >> 4, l16 = lane & 15;
    const u16* Qh = Qb + (size_t)bh * N_ * DH_;
    const u16* Kh = Kb + (size_t)bh * N_ * DH_;
    const u16* Vh = Vb + (size_t)bh * N_ * DH_;
    __shared__ __align__(16) u16 sK[64 * 64];
    __shared__ __align__(16) u16 sV[64 * 64];     // transposed [dh][key]
    __shared__ __align__(16) u16 sP[4][16 * 64];  // wave-private P
    __shared__ int sevt[64];

    // Q A-frags in registers: A[m=lane&15][k=quad*8+j]
    short8 aq0 = *(const short8*)&Qh[(size_t)(q0 + w * 16 + l16) * 64 + quad * 8];
    short8 aq1 = *(const short8*)&Qh[(size_t)(q0 + w * 16 + l16) * 64 + quad * 8 + 32];

    floatx4 zero = {0.f, 0.f, 0.f, 0.f};
    floatx4 accO[4];
#pragma unroll
    for (int d = 0; d < 4; ++d) accO[d] = zero;
    float m_i[4] = {-1e30f, -1e30f, -1e30f, -1e30f};
    float l_i[4] = {0.f, 0.f, 0.f, 0.f};

    int ktiles = blockIdx.x + 1;
    for (int kt = 0; kt < ktiles; ++kt) {
        int k0 = kt * 64;
#pragma unroll
        for (int it = 0; it < 2; ++it) {
            int e = (tid + it * 256) * 8;
            int r = e >> 6, c = e & 63;
            *(uint4*)&sK[e] = *(const uint4*)&Kh[(size_t)(k0 + r) * 64 + c];
            uint4 vv = *(const uint4*)&Vh[(size_t)(k0 + r) * 64 + c];
            sV[(c + 0) * 64 + r] = (u16)(vv.x & 0xFFFF);
            sV[(c + 1) * 64 + r] = (u16)(vv.x >> 16);
            sV[(c + 2) * 64 + r] = (u16)(vv.y & 0xFFFF);
            sV[(c + 3) * 64 + r] = (u16)(vv.y >> 16);
            sV[(c + 4) * 64 + r] = (u16)(vv.z & 0xFFFF);
            sV[(c + 5) * 64 + r] = (u16)(vv.z >> 16);
            sV[(c + 6) * 64 + r] = (u16)(vv.w & 0xFFFF);
            sV[(c + 7) * 64 + r] = (u16)(vv.w >> 16);
        }
        if (tid < 64) sevt[tid] = evt[b * M_ + k0 + tid];
        __syncthreads();

        floatx4 lg[4];
        int nbase = q0 + w * 16 + quad * 4;
#pragma unroll
        for (int s = 0; s < 4; ++s) {
            floatx4 sc = zero;
            short8 bk0 = *(const short8*)&sK[(s * 16 + l16) * 64 + quad * 8];
            short8 bk1 = *(const short8*)&sK[(s * 16 + l16) * 64 + quad * 8 + 32];
            sc = __builtin_amdgcn_mfma_f32_16x16x32_bf16(aq0, bk0, sc, 0, 0, 0);
            sc = __builtin_amdgcn_mfma_f32_16x16x32_bf16(aq1, bk1, sc, 0, 0, 0);
            int m = k0 + s * 16 + l16;
            int ev = sevt[s * 16 + l16];
#pragma unroll
            for (int r = 0; r < 4; ++r) {
                int n = nbase + r;
                bool keep = (m <= n) && (n < ev);
                lg[s][r] = keep ? sc[r] * 0.125f : -1e30f;
            }
        }
        float mnew[4], scale[4], rs[4];
#pragma unroll
        for (int r = 0; r < 4; ++r) {
            float mx = fmaxf(fmaxf(lg[0][r], lg[1][r]), fmaxf(lg[2][r], lg[3][r]));
#pragma unroll
            for (int d = 1; d < 16; d <<= 1) mx = fmaxf(mx, __shfl_xor(mx, d));
            mnew[r] = fmaxf(m_i[r], mx);
            scale[r] = __expf(m_i[r] - mnew[r]);
            m_i[r] = mnew[r];
            rs[r] = 0.f;
        }
#pragma unroll
        for (int s = 0; s < 4; ++s)
#pragma unroll
            for (int r = 0; r < 4; ++r) {
                float p = __expf(lg[s][r] - mnew[r]);
                rs[r] += p;
                sP[w][(quad * 4 + r) * 64 + s * 16 + l16] = f2b(p);
            }
#pragma unroll
        for (int r = 0; r < 4; ++r) {
            float t_ = rs[r];
#pragma unroll
            for (int d = 1; d < 16; d <<= 1) t_ += __shfl_xor(t_, d);
            l_i[r] = l_i[r] * scale[r] + t_;
        }
#pragma unroll
        for (int dd = 0; dd < 4; ++dd) {
            accO[dd][0] *= scale[0]; accO[dd][1] *= scale[1];
            accO[dd][2] *= scale[2]; accO[dd][3] *= scale[3];
        }
        // P: C-layout -> A-layout via wave-private LDS round-trip
        short8 ap0 = *(const short8*)&sP[w][l16 * 64 + quad * 8];
        short8 ap1 = *(const short8*)&sP[w][l16 * 64 + quad * 8 + 32];
#pragma unroll
        for (int dd = 0; dd < 4; ++dd) {
            short8 bv0 = *(const short8*)&sV[(dd * 16 + l16) * 64 + quad * 8];
            short8 bv1 = *(const short8*)&sV[(dd * 16 + l16) * 64 + quad * 8 + 32];
            accO[dd] = __builtin_amdgcn_mfma_f32_16x16x32_bf16(ap0, bv0, accO[dd], 0, 0, 0);
            accO[dd] = __builtin_amdgcn_mfma_f32_16x16x32_bf16(ap1, bv1, accO[dd], 0, 0, 0);
        }
        __syncthreads();
    }
#pragma unroll
    for (int dd = 0; dd < 4; ++dd)
#pragma unroll
        for (int r = 0; r < 4; ++r) {
            int n = q0 + w * 16 + quad * 4 + r;
            int col = h * 64 + dd * 16 + l16;
            Ob[((size_t)b * N_ + n) * D_ + col] = f2b(accO[dd][r] / l_i[r]);
        }
}

// ---------------------------------------------------------------- launch
extern "C" void kernel_launch(void* const* d_in, const int* in_sizes, int n_in,
                              void* d_out, int out_size, void* d_ws, size_t ws_size,
                              hipStream_t stream)
{
    (void)in_sizes; (void)n_in; (void)out_size; (void)ws_size;
    const float* X  = (const float*)d_in[0];
    const float* Wq = (const float*)d_in[1];
    const float* Wk = (const float*)d_in[2];
    const float* Wv = (const float*)d_in[3];
    const float* Wo = (const float*)d_in[4];
    const float* gq = (const float*)d_in[5];
    const float* bq = (const float*)d_in[6];
    const float* gk = (const float*)d_in[7];
    const float* bk = (const float*)d_in[8];
    // d_in[9] cache_k, d_in[10] cache_v, d_in[11] start_pos: start_pos==0 here.

    char* p = (char*)d_ws;
    const size_t SZ_XH = (size_t)ROWS_ * D_ * 2;   // 8 MiB bf16
    const size_t SZ_W  = (size_t)D_ * D_ * 2;      // 2 MiB bf16
    const size_t SZ_Y  = (size_t)ROWS_ * D_ * 4;   // 16 MiB fp32
    const size_t SZ_PK = (size_t)ROWS_ * D_ * 2;   // 8 MiB bf16
    const size_t SZ_H0 = (size_t)ROWS_ * 64 * 4;   // 1 MiB fp32

    size_t o = 0;
    u16* Xhi = (u16*)(p + o); o += SZ_XH;
    u16* Xlo = (u16*)(p + o); o += SZ_XH;
    u16* Wqh = (u16*)(p + o); o += SZ_W;
    u16* Wql = (u16*)(p + o); o += SZ_W;
    u16* Wkh = (u16*)(p + o); o += SZ_W;
    u16* Wkl = (u16*)(p + o); o += SZ_W;
    u16* Wvh = (u16*)(p + o); o += SZ_W;
    u16* Woh = (u16*)(p + o); o += SZ_W;
    float* Yq = (float*)(p + o); size_t oYq = o; o += SZ_Y;
    float* Yk = (float*)(p + o); o += SZ_Y;
    float* Yv = (float*)(p + o); o += SZ_Y;
    u16* Qb = (u16*)(p + o); o += SZ_PK;
    u16* Kb = (u16*)(p + o); o += SZ_PK;
    u16* Vb = (u16*)(p + o); o += SZ_PK;
    float* q0s = (float*)(p + o); o += SZ_H0;
    float* k0s = (float*)(p + o); o += SZ_H0;
    float* Pp  = (float*)(p + o); o += (size_t)B_ * 8 * M_ * 4;
    int* evt   = (int*)(p + o);  o += (size_t)B_ * M_ * 4;
    // overlays (dead slots):
    float* S = (float*)(p + oYq);   // 32 MiB over Yq+Yk, used after LN
    u16* Ob  = Xhi;                 // 8 MiB over Xhi, used after all X-GEMMs

    cast_x_kernel<<<ROWS_ * D_ / (256 * 4), 256, 0, stream>>>(X, Xhi, Xlo);
    dim3 wgrid(32, 32), wblk(32, 32);
    cast_w_kernel<<<wgrid, wblk, 0, stream>>>(Wq, Wqh, Wql, 1);
    cast_w_kernel<<<wgrid, wblk, 0, stream>>>(Wk, Wkh, Wkl, 1);
    cast_w_kernel<<<wgrid, wblk, 0, stream>>>(Wv, Wvh, nullptr, 0);
    cast_w_kernel<<<wgrid, wblk, 0, stream>>>(Wo, Woh, nullptr, 0);

    dim3 ggrid(D_ / 128, ROWS_ / 128);
    gemm_kernel<<<ggrid, 256, 0, stream>>>(Xhi, Xlo, Wqh, Wql, 1, Yq);
    gemm_kernel<<<ggrid, 256, 0, stream>>>(Xhi, Xlo, Wkh, Wkl, 1, Yk);
    gemm_kernel<<<ggrid, 256, 0, stream>>>(Xhi, nullptr, Wvh, nullptr, 0, Yv);

    lnpack_kernel<<<ROWS_, 256, 0, stream>>>(Yq, gq, bq, Qb, q0s, 1);
    lnpack_kernel<<<ROWS_, 256, 0, stream>>>(Yk, gk, bk, Kb, k0s, 1);
    lnpack_kernel<<<ROWS_, 256, 0, stream>>>(Yv, nullptr, nullptr, Vb, nullptr, 0);

    s_kernel<<<dim3(M_ / 16, N_ / 16, B_), dim3(16, 16), 0, stream>>>(q0s, k0s, S);
    p_kernel<<<dim3(M_ / 256, 8, B_), 256, 0, stream>>>(S, Pp);
    evict_kernel<<<B_, 256, 0, stream>>>(S, Pp, evt);

    flash_kernel<<<dim3(N_ / 64, B_ * H_), 256, 0, stream>>>(Qb, Kb, Vb, evt, Ob);
    gemm_kernel<<<ggrid, 256, 0, stream>>>(Ob, nullptr, Woh, nullptr, 0, (float*)d_out);
}